// Round 1
// baseline (671.147 us; speedup 1.0000x reference)
//
#include <hip/hip_runtime.h>
#include <cmath>

#define B_TOT 16384
#define D_DIM 64
#define K_DIM 128
#define NC_DIM 64
#define F_DIM 256

// M[n][f] = sum_k q_feat_w[k][f] * cq[n][k]   (fp64 accumulate, f32 store)
__global__ void mproj_kernel(const float* __restrict__ qfw,
                             const float* __restrict__ cq,
                             float* __restrict__ M) {
  const int n = blockIdx.x;   // 0..63
  const int f = threadIdx.x;  // 0..255
  const float* __restrict__ cqn = cq + n * K_DIM;
  double acc = 0.0;
#pragma unroll 8
  for (int k = 0; k < K_DIM; ++k)
    acc = fma((double)qfw[k * F_DIM + f], (double)cqn[k], acc);
  M[n * F_DIM + f] = (float)acc;
}

__global__ __launch_bounds__(1024) void fused_kernel(
    const float* __restrict__ z, const float* __restrict__ feat,
    const float* __restrict__ qzw, const float* __restrict__ qzb,
    const float* __restrict__ qfb, const float* __restrict__ gamma,
    const float* __restrict__ cq, const float* __restrict__ Mf,
    float* __restrict__ out) {
  // static LDS, 58112 B total; score buffer overlays dead q/feat tiles
  __shared__ __align__(16) unsigned char smem[58112];
  float (*z_lds)[65]  = (float (*)[65])(smem);            // 16640
  float (*q_lds)[129] = (float (*)[129])(smem + 16640);   // 33024 -> 49664
  float (*fchunk)[33] = (float (*)[33])(smem + 49664);    //  8448 -> 58112
  double (*s_lds)[65] = (double (*)[65])(smem + 16640);   // overlay, 33280
  double* sum_lds     = (double*)(smem + 49920);
  int* arg_lds        = (int*)(smem + 50432);

  const int t = threadIdx.x;
  const int lane = t & 63;                                   // = b within tile
  const int wv = __builtin_amdgcn_readfirstlane(t >> 6);     // wave id 0..15
  const int b0 = blockIdx.x * 64;

  // ---- stage z tile (coalesced) ----
  for (int i = t; i < 64 * 64; i += 1024)
    z_lds[i >> 6][i & 63] = z[(size_t)b0 * D_DIM + i];
  __syncthreads();

  float zr[64];
#pragma unroll
  for (int j = 0; j < 64; ++j) zr[j] = z_lds[lane][j];

  // ---- feature term: facc[jn] = sum_f feat[b][f]*M[n][f], n = wv + 16*jn ----
  float facc[4] = {0.f, 0.f, 0.f, 0.f};
  for (int c = 0; c < 8; ++c) {
    __syncthreads();  // WAR guard on fchunk
    for (int i = t; i < 64 * 32; i += 1024) {
      const int r = i >> 5, col = i & 31;
      fchunk[r][col] = feat[(size_t)(b0 + r) * F_DIM + c * 32 + col];
    }
    __syncthreads();
#pragma unroll
    for (int fb = 0; fb < 32; fb += 8) {
      float rf[8];
#pragma unroll
      for (int u = 0; u < 8; ++u) rf[u] = fchunk[lane][fb + u];
#pragma unroll
      for (int jn = 0; jn < 4; ++jn) {
        const float* __restrict__ Mn = Mf + (wv + 16 * jn) * F_DIM + c * 32 + fb;
#pragma unroll
        for (int u = 0; u < 8; ++u) facc[jn] = fmaf(rf[u], Mn[u], facc[jn]);
      }
    }
  }

  // ---- phase 1: q[b][k] = qzb+qfb + sum_i z_i*(qzw[k][i] + sum_j G[k][i][j] z_j)
  // k wave-uniform -> Gamma/qzw/biases via scalar loads; z in VGPRs.
  for (int kk = 0; kk < 8; ++kk) {
    const int k = wv * 8 + kk;
    const float* __restrict__ gk = gamma + (size_t)k * (D_DIM * D_DIM);
    const float* __restrict__ qzwk = qzw + k * D_DIM;
    float acc = qzb[k] + qfb[k];
#pragma unroll 2
    for (int i = 0; i < 64; ++i) {
      const float* __restrict__ gr = gk + i * 64;
      float w0 = 0.f, w1 = 0.f, w2 = 0.f, w3 = 0.f;
#pragma unroll
      for (int j = 0; j < 64; j += 4) {
        w0 = fmaf(gr[j + 0], zr[j + 0], w0);
        w1 = fmaf(gr[j + 1], zr[j + 1], w1);
        w2 = fmaf(gr[j + 2], zr[j + 2], w2);
        w3 = fmaf(gr[j + 3], zr[j + 3], w3);
      }
      const float w = ((w0 + w1) + (w2 + w3)) + qzwk[i];
      acc = fmaf(z_lds[lane][i], w, acc);
    }
    q_lds[lane][k] = acc;
  }
  __syncthreads();

  // ---- per-row scalars (fp64) ----
  double z_sq;
  {
    double a0 = 0.0, a1 = 0.0;
#pragma unroll
    for (int i = 0; i < 64; i += 2) {
      const double z0 = (double)zr[i], z1 = (double)zr[i + 1];
      a0 = fma(z0, z0, a0);
      a1 = fma(z1, z1, a1);
    }
    z_sq = a0 + a1;
  }
  const double EPS = 0.001;
  const double SQRTK = sqrt(128.0);
  double tau = SQRTK * fmax(1.0 - z_sq, 0.001) * 0.5;
  tau = fmax(tau, 0.01);
  const double r2 = fmin(z_sq, 1.0 - EPS);
  const double lam = 2.0 / (1.0 - r2 + EPS);

  // ---- phase 2: scores (fp64 nonlinear path), n = wv + 16*jn ----
  double sc[4];
#pragma unroll 1
  for (int jn = 0; jn < 4; ++jn) {
    const int n = wv + 16 * jn;
    const float* __restrict__ cqn = cq + n * K_DIM;  // wave-uniform -> scalar
    double csq0 = 0.0, csq1 = 0.0, dsq0 = 0.0, dsq1 = 0.0;
#pragma unroll
    for (int i = 0; i < 64; i += 2) {
      const double c0 = (double)cqn[i];
      const double c1 = (double)cqn[i + 1];
      csq0 = fma(c0, c0, csq0);
      csq1 = fma(c1, c1, csq1);
      const double d0 = (double)zr[i] - c0;
      const double d1 = (double)zr[i + 1] - c1;
      dsq0 = fma(d0, d0, dsq0);
      dsq1 = fma(d1, d1, dsq1);
    }
    const double c_sq = csq0 + csq1;
    const double dist_sq = dsq0 + dsq1;

    float qd0 = 0.f, qd1 = 0.f, qd2 = 0.f, qd3 = 0.f;
#pragma unroll 8
    for (int kq = 0; kq < 128; kq += 4) {
      qd0 = fmaf(q_lds[lane][kq + 0], cqn[kq + 0], qd0);
      qd1 = fmaf(q_lds[lane][kq + 1], cqn[kq + 1], qd1);
      qd2 = fmaf(q_lds[lane][kq + 2], cqn[kq + 2], qd2);
      qd3 = fmaf(q_lds[lane][kq + 3], cqn[kq + 3], qd3);
    }
    const double qtot = (double)((qd0 + qd1) + (qd2 + qd3)) + (double)facc[jn];

    const double denom = (1.0 - z_sq) * (1.0 - c_sq);
    double arg = 1.0 + 2.0 * dist_sq / (denom + EPS);
    arg = fmax(arg, 1.0 + EPS);
    const double dist = log(arg + sqrt(arg * arg - 1.0));  // arccosh
    sc[jn] = -dist / tau + (qtot / lam) / SQRTK;
  }
  __syncthreads();  // all q_lds/fchunk reads done before overlay write
#pragma unroll
  for (int jn = 0; jn < 4; ++jn) s_lds[lane][wv + 16 * jn] = sc[jn];
  __syncthreads();

  // ---- phase 3: softmax + argmax per row (fp64) ----
  if (t < 64) {
    const int b = t;
    double mx = s_lds[b][0];
    int am = 0;
#pragma unroll 4
    for (int n = 1; n < 64; ++n) {
      const double v = s_lds[b][n];
      if (v > mx) { mx = v; am = n; }  // strict '>' == np.argmax first-wins
    }
    double sum = 0.0;
#pragma unroll 4
    for (int n = 0; n < 64; ++n) {
      const double e = exp(s_lds[b][n] - mx);
      s_lds[b][n] = e;
      sum += e;
    }
    sum_lds[b] = sum;
    arg_lds[b] = am;
  }
  __syncthreads();
  for (int idx = t; idx < 64 * 64; idx += 1024) {
    const int b = idx >> 6, n = idx & 63;
    out[(size_t)(b0 + b) * NC_DIM + n] = (float)(s_lds[b][n] / sum_lds[b]);
  }
  if (t < 64) out[(size_t)B_TOT * NC_DIM + b0 + t] = (float)arg_lds[t];
}

extern "C" void kernel_launch(void* const* d_in, const int* in_sizes, int n_in,
                              void* d_out, int out_size, void* d_ws, size_t ws_size,
                              hipStream_t stream) {
  const float* z = (const float*)d_in[0];
  const float* feat = (const float*)d_in[1];
  const float* qzw = (const float*)d_in[2];
  const float* qzb = (const float*)d_in[3];
  const float* qfw = (const float*)d_in[4];
  const float* qfb = (const float*)d_in[5];
  const float* gamma = (const float*)d_in[6];
  const float* cq = (const float*)d_in[7];
  float* out = (float*)d_out;
  float* Mf = (float*)d_ws;  // 64*256 floats = 64 KiB scratch

  mproj_kernel<<<dim3(NC_DIM), dim3(F_DIM), 0, stream>>>(qfw, cq, Mf);
  fused_kernel<<<dim3(B_TOT / 64), dim3(1024), 0, stream>>>(
      z, feat, qzw, qzb, qfb, gamma, cq, Mf, out);
}

// Round 2
// 360.733 us; speedup vs baseline: 1.8605x; 1.8605x over previous
//
#include <hip/hip_runtime.h>
#include <cmath>

#define B_TOT 16384
#define D_DIM 64
#define K_DIM 128
#define NC_DIM 64
#define F_DIM 256

typedef unsigned short ushort_t;
typedef unsigned int uint_t;
typedef __attribute__((ext_vector_type(8))) short bf16x8;
typedef __attribute__((ext_vector_type(4))) float f32x4;

// workspace layout (bytes)
#define WS_MF 0            // float[64][256]   = 65536
#define WS_W2 65536        // float[64][64]    = 16384
#define WS_BIAS 81920      // double[64]       = 512
#define WS_CSQ 82432       // double[64]       = 512
#define WS_GPK 131072      // ushort, 32B packs {8 hi,8 lo} per (m,jb): 2 MiB
// total 2228224 B required in d_ws

// ---------------- prep: gamma->bf16 hi/lo packs, M=qfw*cq^T, W2=cq*qzw, bias, csq
__global__ void prep_kernel(const float* __restrict__ gamma,
                            const float* __restrict__ qfw,
                            const float* __restrict__ cq,
                            const float* __restrict__ qzw,
                            const float* __restrict__ qzb,
                            const float* __restrict__ qfb,
                            char* __restrict__ ws) {
  const int bid = blockIdx.x, tid = threadIdx.x;
  if (bid < 256) {
    // gamma conversion: tg indexes (m, jb); pack = {8 hi bf16, 8 lo bf16} = 32 B
    const int tg = bid * 256 + tid;  // 0..65535
    const float* __restrict__ src = gamma + (size_t)tg * 8;
    uint_t hi[8], lo[8];
#pragma unroll
    for (int e = 0; e < 8; ++e) {
      const float v = src[e];
      const uint_t h = __float_as_uint(v) >> 16;
      const float hr = __uint_as_float(h << 16);
      hi[e] = h;
      lo[e] = __float_as_uint(v - hr) >> 16;
    }
    uint_t* dst = (uint_t*)(ws + WS_GPK + (size_t)tg * 32);
    dst[0] = hi[0] | (hi[1] << 16);
    dst[1] = hi[2] | (hi[3] << 16);
    dst[2] = hi[4] | (hi[5] << 16);
    dst[3] = hi[6] | (hi[7] << 16);
    dst[4] = lo[0] | (lo[1] << 16);
    dst[5] = lo[2] | (lo[3] << 16);
    dst[6] = lo[4] | (lo[5] << 16);
    dst[7] = lo[6] | (lo[7] << 16);
  } else if (bid < 320) {
    // M[n][f] = sum_k qfw[k][f] * cq[n][k]
    const int n = bid - 256, f = tid;
    const float* __restrict__ cqn = cq + n * K_DIM;
    double acc = 0.0;
#pragma unroll 8
    for (int k = 0; k < K_DIM; ++k)
      acc = fma((double)qfw[k * F_DIM + f], (double)cqn[k], acc);
    ((float*)(ws + WS_MF))[n * F_DIM + f] = (float)acc;
  } else {
    const int n = bid - 320;
    const float* __restrict__ cqn = cq + n * K_DIM;
    if (tid < 64) {
      // W2[n][i] = sum_k cq[n][k] * qzw[k][i]
      double acc = 0.0;
#pragma unroll 8
      for (int k = 0; k < K_DIM; ++k)
        acc = fma((double)cqn[k], (double)qzw[k * D_DIM + tid], acc);
      ((float*)(ws + WS_W2))[n * D_DIM + tid] = (float)acc;
    } else if (tid == 64) {
      double b = 0.0;
      for (int k = 0; k < K_DIM; ++k)
        b = fma((double)qzb[k] + (double)qfb[k], (double)cqn[k], b);
      ((double*)(ws + WS_BIAS))[n] = b;
    } else if (tid == 65) {
      double c = 0.0;
      for (int d = 0; d < D_DIM; ++d)
        c = fma((double)cqn[d], (double)cqn[d], c);
      ((double*)(ws + WS_CSQ))[n] = c;
    }
  }
}

// ---------------- fused main kernel
__global__ __launch_bounds__(1024, 4) void fused_kernel(
    const float* __restrict__ z, const float* __restrict__ feat,
    const float* __restrict__ cq, const char* __restrict__ ws,
    float* __restrict__ out) {
  __shared__ __align__(16) unsigned char smem[58112];
  float (*z_lds)[65]  = (float (*)[65])(smem);            // 16640
  float (*q_lds)[129] = (float (*)[129])(smem + 16640);   // 33024 -> 49664
  float (*fchunk)[33] = (float (*)[33])(smem + 49664);    //  8448 -> 58112
  double (*s_lds)[65] = (double (*)[65])(smem + 16640);   // overlay 33280
  double* sum_lds     = (double*)(smem + 49920);
  int* arg_lds        = (int*)(smem + 50432);

  const float* __restrict__ Mf = (const float*)(ws + WS_MF);
  const float* __restrict__ W2 = (const float*)(ws + WS_W2);
  const double* __restrict__ biasd = (const double*)(ws + WS_BIAS);
  const double* __restrict__ csqd = (const double*)(ws + WS_CSQ);
  const char* __restrict__ gpk = ws + WS_GPK;

  const int t = threadIdx.x;
  const int lane = t & 63;
  const int wv = __builtin_amdgcn_readfirstlane(t >> 6);  // 0..15
  const int b0 = blockIdx.x * 64;

  // ---- stage z tile ----
  for (int i = t; i < 64 * 64; i += 1024)
    z_lds[i >> 6][i & 63] = z[(size_t)b0 * D_DIM + i];
  __syncthreads();

  // ---- phase 1: q_gamma[b,k] via split-bf16 MFMA 16x16x32 ----
  // wave roles: ntile = wv&3 (b = ntile*16 + col), mgrp = wv>>2 (k in [mgrp*32, +32))
  {
    const int ntile = wv & 3, mgrp = wv >> 2;
    const int q4 = lane >> 4, col = lane & 15;
    const int bcol = ntile * 16 + col;

    // z B-fragments, split hi/lo: B[kdim = q4*8+e][n=col] = z[bcol][ks*32 + q4*8 + e]
    bf16x8 Bhi[2], Blo[2];
#pragma unroll
    for (int ks = 0; ks < 2; ++ks)
#pragma unroll
      for (int e = 0; e < 8; ++e) {
        const float v = z_lds[bcol][ks * 32 + q4 * 8 + e];
        const uint_t h = __float_as_uint(v) >> 16;
        const float hr = __uint_as_float(h << 16);
        Bhi[ks][e] = (short)h;
        Blo[ks][e] = (short)(__float_as_uint(v - hr) >> 16);
      }
    // z multipliers for the epilogue: i = mtp*16 + 4*q4 + r, ci = mtp*4 + r
    float zc[16];
#pragma unroll
    for (int ci = 0; ci < 16; ++ci)
      zc[ci] = z_lds[bcol][(ci >> 2) * 16 + 4 * q4 + (ci & 3)];

    for (int kloc = 0; kloc < 32; ++kloc) {
      const int k = mgrp * 32 + kloc;
      const char* rowbase = gpk + ((size_t)k * 64 + col) * 256 + q4 * 32;
      float ap = 0.f;
#pragma unroll
      for (int mtp = 0; mtp < 4; ++mtp) {
        const bf16x8* pa = (const bf16x8*)(rowbase + mtp * 16 * 256);
        f32x4 C = {0.f, 0.f, 0.f, 0.f};
        C = __builtin_amdgcn_mfma_f32_16x16x32_bf16(pa[0], Bhi[0], C, 0, 0, 0);
        C = __builtin_amdgcn_mfma_f32_16x16x32_bf16(pa[0], Blo[0], C, 0, 0, 0);
        C = __builtin_amdgcn_mfma_f32_16x16x32_bf16(pa[1], Bhi[0], C, 0, 0, 0);
        C = __builtin_amdgcn_mfma_f32_16x16x32_bf16(pa[8], Bhi[1], C, 0, 0, 0);
        C = __builtin_amdgcn_mfma_f32_16x16x32_bf16(pa[8], Blo[1], C, 0, 0, 0);
        C = __builtin_amdgcn_mfma_f32_16x16x32_bf16(pa[9], Bhi[1], C, 0, 0, 0);
        ap += C[0] * zc[mtp * 4 + 0] + C[1] * zc[mtp * 4 + 1] +
              C[2] * zc[mtp * 4 + 2] + C[3] * zc[mtp * 4 + 3];
      }
      ap += __shfl_xor(ap, 16, 64);
      ap += __shfl_xor(ap, 32, 64);
      if (q4 == 0) q_lds[bcol][k] = ap;
    }
  }

  // ---- feature term: facc[jn] = sum_f feat[b][f]*M[n][f], n = wv + 16*jn ----
  float facc[4] = {0.f, 0.f, 0.f, 0.f};
  for (int c = 0; c < 8; ++c) {
    __syncthreads();
    for (int i = t; i < 64 * 32; i += 1024) {
      const int r = i >> 5, col = i & 31;
      fchunk[r][col] = feat[(size_t)(b0 + r) * F_DIM + c * 32 + col];
    }
    __syncthreads();
#pragma unroll
    for (int fb = 0; fb < 32; fb += 8) {
      float rf[8];
#pragma unroll
      for (int u = 0; u < 8; ++u) rf[u] = fchunk[lane][fb + u];
#pragma unroll
      for (int jn = 0; jn < 4; ++jn) {
        const float* __restrict__ Mn = Mf + (wv + 16 * jn) * F_DIM + c * 32 + fb;
#pragma unroll
        for (int u = 0; u < 8; ++u) facc[jn] = fmaf(rf[u], Mn[u], facc[jn]);
      }
    }
  }
  __syncthreads();  // q_lds complete + fchunk done before phase 2

  // ---- per-row scalars ----
  float zr[64];
#pragma unroll
  for (int j = 0; j < 64; ++j) zr[j] = z_lds[lane][j];
  double z_sq;
  {
    double a0 = 0.0, a1 = 0.0;
#pragma unroll
    for (int i = 0; i < 64; i += 2) {
      a0 = fma((double)zr[i], (double)zr[i], a0);
      a1 = fma((double)zr[i + 1], (double)zr[i + 1], a1);
    }
    z_sq = a0 + a1;
  }
  const double EPS = 0.001;
  const double SQRTK = sqrt(128.0);
  double tau = SQRTK * fmax(1.0 - z_sq, 0.001) * 0.5;
  tau = fmax(tau, 0.01);
  const double r2 = fmin(z_sq, 1.0 - EPS);
  const double lam = 2.0 / (1.0 - r2 + EPS);

  // ---- q . cq dot (k-outer, 4 n inner; conflict-free b32 LDS reads) ----
  float qd[4] = {0.f, 0.f, 0.f, 0.f};
#pragma unroll 4
  for (int kq = 0; kq < 128; kq += 4) {
    const float q0 = q_lds[lane][kq + 0], q1 = q_lds[lane][kq + 1];
    const float q2 = q_lds[lane][kq + 2], q3 = q_lds[lane][kq + 3];
#pragma unroll
    for (int jn = 0; jn < 4; ++jn) {
      const float* __restrict__ cqn = cq + (wv + 16 * jn) * K_DIM;
      qd[jn] = fmaf(q0, cqn[kq + 0], qd[jn]);
      qd[jn] = fmaf(q1, cqn[kq + 1], qd[jn]);
      qd[jn] = fmaf(q2, cqn[kq + 2], qd[jn]);
      qd[jn] = fmaf(q3, cqn[kq + 3], qd[jn]);
    }
  }

  // ---- phase 2: scores ----
  double sc[4];
#pragma unroll 1
  for (int jn = 0; jn < 4; ++jn) {
    const int n = wv + 16 * jn;
    const float* __restrict__ cqn = cq + n * K_DIM;
    double zc0 = 0.0, zc1 = 0.0;
    float l0 = 0.f, l1 = 0.f;
    const float* __restrict__ w2n = W2 + n * D_DIM;
#pragma unroll
    for (int i = 0; i < 64; i += 2) {
      zc0 = fma((double)zr[i], (double)cqn[i], zc0);
      zc1 = fma((double)zr[i + 1], (double)cqn[i + 1], zc1);
      l0 = fmaf(zr[i], w2n[i], l0);
      l1 = fmaf(zr[i + 1], w2n[i + 1], l1);
    }
    const double c_sq = csqd[n];
    double dist_sq = z_sq + c_sq - 2.0 * (zc0 + zc1);
    const double denom = (1.0 - z_sq) * (1.0 - c_sq);
    double arg = 1.0 + 2.0 * dist_sq / (denom + EPS);
    arg = fmax(arg, 1.0 + EPS);
    const double dist = log(arg + sqrt(arg * arg - 1.0));
    const double qtot = (double)qd[jn] + (double)facc[jn] + (double)(l0 + l1) + biasd[n];
    sc[jn] = -dist / tau + (qtot / lam) / SQRTK;
  }
  __syncthreads();  // all q_lds reads done before s_lds overlay
#pragma unroll
  for (int jn = 0; jn < 4; ++jn) s_lds[lane][wv + 16 * jn] = sc[jn];
  __syncthreads();

  // ---- phase 3: softmax + argmax ----
  if (t < 64) {
    const int b = t;
    double mx = s_lds[b][0];
    int am = 0;
#pragma unroll 4
    for (int n = 1; n < 64; ++n) {
      const double v = s_lds[b][n];
      if (v > mx) { mx = v; am = n; }
    }
    double sum = 0.0;
#pragma unroll 4
    for (int n = 0; n < 64; ++n) {
      const double e = exp(s_lds[b][n] - mx);
      s_lds[b][n] = e;
      sum += e;
    }
    sum_lds[b] = sum;
    arg_lds[b] = am;
  }
  __syncthreads();
  for (int idx = t; idx < 64 * 64; idx += 1024) {
    const int b = idx >> 6, n = idx & 63;
    out[(size_t)(b0 + b) * NC_DIM + n] = (float)(s_lds[b][n] / sum_lds[b]);
  }
  if (t < 64) out[(size_t)B_TOT * NC_DIM + b0 + t] = (float)arg_lds[t];
}

extern "C" void kernel_launch(void* const* d_in, const int* in_sizes, int n_in,
                              void* d_out, int out_size, void* d_ws, size_t ws_size,
                              hipStream_t stream) {
  const float* z = (const float*)d_in[0];
  const float* feat = (const float*)d_in[1];
  const float* qzw = (const float*)d_in[2];
  const float* qzb = (const float*)d_in[3];
  const float* qfw = (const float*)d_in[4];
  const float* qfb = (const float*)d_in[5];
  const float* gamma = (const float*)d_in[6];
  const float* cq = (const float*)d_in[7];
  float* out = (float*)d_out;
  char* ws = (char*)d_ws;

  prep_kernel<<<dim3(384), dim3(256), 0, stream>>>(gamma, qfw, cq, qzw, qzb, qfb, ws);
  fused_kernel<<<dim3(B_TOT / 64), dim3(1024), 0, stream>>>(z, feat, cq, ws, out);
}

// Round 3
// 200.447 us; speedup vs baseline: 3.3483x; 1.7996x over previous
//
#include <hip/hip_runtime.h>
#include <cmath>

#define B_TOT 16384
#define D_DIM 64
#define K_DIM 128
#define NC_DIM 64
#define F_DIM 256

typedef unsigned int uint_t;
typedef __attribute__((ext_vector_type(8))) short bf16x8;
typedef __attribute__((ext_vector_type(4))) float f32x4;

// workspace layout (bytes)
#define WS_MF 0            // float[64][256]   = 65536
#define WS_W2 65536        // float[64][64]    = 16384
#define WS_BIAS 81920      // double[64]       = 512
#define WS_CSQ 82432       // double[64]       = 512
#define WS_GPK 131072      // swizzled gamma fragments, 2 MiB
// fragment addr: ((k*16 + mtp*4 + slot)*64 + lane)*16 bytes
// slot: 0 = hi(j 0..31), 1 = lo(j 0..31), 2 = hi(j 32..63), 3 = lo(j 32..63)
// lane (q4=lane>>4, col=lane&15) holds gamma_part[k][mtp*16+col][jbase + q4*8 .. +8]

// ---------------- prep ----------------
__global__ __launch_bounds__(256) void prep_kernel(
    const float* __restrict__ gamma, const float* __restrict__ qfw,
    const float* __restrict__ cq, const float* __restrict__ qzw,
    const float* __restrict__ qzb, const float* __restrict__ qfb,
    char* __restrict__ ws) {
  const int bid = blockIdx.x, tid = threadIdx.x;
  if (bid < 128) {
    // gamma swizzle for k = bid
    __shared__ float g[64][65];
    const int k = bid;
    const float* __restrict__ gk = gamma + (size_t)k * 4096;
    for (int i = tid; i < 4096; i += 256) g[i >> 6][i & 63] = gk[i];
    __syncthreads();
    const int mtp = tid >> 6, l = tid & 63, q4 = l >> 4, col = l & 15;
    const int i = mtp * 16 + col;
    uint_t* __restrict__ dst =
        (uint_t*)(ws + WS_GPK + ((size_t)(k * 16 + mtp * 4) * 64 + l) * 16);
#pragma unroll
    for (int ks = 0; ks < 2; ++ks) {
      uint_t hi[8], lo[8];
#pragma unroll
      for (int e = 0; e < 8; ++e) {
        const float v = g[i][ks * 32 + q4 * 8 + e];
        const uint_t h = __float_as_uint(v) >> 16;
        hi[e] = h;
        lo[e] = __float_as_uint(v - __uint_as_float(h << 16)) >> 16;
      }
      uint_t* dhi = dst + (ks * 2 + 0) * 256;  // slot stride = 1024 B
      uint_t* dlo = dst + (ks * 2 + 1) * 256;
      dhi[0] = hi[0] | (hi[1] << 16);
      dhi[1] = hi[2] | (hi[3] << 16);
      dhi[2] = hi[4] | (hi[5] << 16);
      dhi[3] = hi[6] | (hi[7] << 16);
      dlo[0] = lo[0] | (lo[1] << 16);
      dlo[1] = lo[2] | (lo[3] << 16);
      dlo[2] = lo[4] | (lo[5] << 16);
      dlo[3] = lo[6] | (lo[7] << 16);
    }
  } else if (bid < 192) {
    // M[n][f] = sum_k qfw[k][f] * cq[n][k]
    const int n = bid - 128, f = tid;
    const float* __restrict__ cqn = cq + n * K_DIM;
    double acc = 0.0;
#pragma unroll 8
    for (int k = 0; k < K_DIM; ++k)
      acc = fma((double)qfw[k * F_DIM + f], (double)cqn[k], acc);
    ((float*)(ws + WS_MF))[n * F_DIM + f] = (float)acc;
  } else {
    const int n = bid - 192;
    const float* __restrict__ cqn = cq + n * K_DIM;
    if (tid < 64) {
      // W2[n][i] = sum_k cq[n][k] * qzw[k][i]
      double acc = 0.0;
#pragma unroll 8
      for (int k = 0; k < K_DIM; ++k)
        acc = fma((double)cqn[k], (double)qzw[k * D_DIM + tid], acc);
      ((float*)(ws + WS_W2))[n * D_DIM + tid] = (float)acc;
    } else if (tid < 128) {
      // bias_n = sum_k (qzb[k]+qfb[k])*cq[n][k] -- one wave, shfl reduce
      const int l = tid - 64;
      double p = ((double)qzb[l] + (double)qfb[l]) * (double)cqn[l] +
                 ((double)qzb[l + 64] + (double)qfb[l + 64]) * (double)cqn[l + 64];
#pragma unroll
      for (int off = 32; off > 0; off >>= 1) p += __shfl_down(p, off, 64);
      if (l == 0) ((double*)(ws + WS_BIAS))[n] = p;
    } else if (tid < 192) {
      const int l = tid - 128;
      double p = (double)cqn[l] * (double)cqn[l];
#pragma unroll
      for (int off = 32; off > 0; off >>= 1) p += __shfl_down(p, off, 64);
      if (l == 0) ((double*)(ws + WS_CSQ))[n] = p;
    }
  }
}

// ---------------- fused main kernel (512 threads = 8 waves) ----------------
__global__ __launch_bounds__(512, 2) void fused_kernel(
    const float* __restrict__ z, const float* __restrict__ feat,
    const float* __restrict__ cq, const char* __restrict__ ws,
    float* __restrict__ out) {
  __shared__ __align__(16) unsigned char smem[58112];
  float (*z_lds)[65]  = (float (*)[65])(smem);            // 16640
  float (*q_lds)[129] = (float (*)[129])(smem + 16640);   // 33024 -> 49664
  float (*fchunk)[33] = (float (*)[33])(smem + 49664);    //  8448 -> 58112
  double (*s_lds)[65] = (double (*)[65])(smem + 16640);   // overlay 33280
  double* sum_lds     = (double*)(smem + 49920);
  int* arg_lds        = (int*)(smem + 50432);

  const float* __restrict__ Mf = (const float*)(ws + WS_MF);
  const float* __restrict__ W2 = (const float*)(ws + WS_W2);
  const double* __restrict__ biasd = (const double*)(ws + WS_BIAS);
  const double* __restrict__ csqd = (const double*)(ws + WS_CSQ);
  const char* __restrict__ gpk = ws + WS_GPK;

  const int t = threadIdx.x;
  const int lane = t & 63;
  const int wv = __builtin_amdgcn_readfirstlane(t >> 6);  // 0..7
  const int b0 = blockIdx.x * 64;

  // ---- stage z tile ----
  for (int i = t; i < 64 * 64; i += 512)
    z_lds[i >> 6][i & 63] = z[(size_t)b0 * D_DIM + i];
  __syncthreads();

  // ---- phase 1: q_gamma[b,k], wave wv owns k in [wv*16, wv*16+16), all 64 b
  {
    const int q4 = lane >> 4, col = lane & 15;
    bf16x8 Bh[4][2], Bl[4][2];
    float zc[4][16];
#pragma unroll
    for (int nt = 0; nt < 4; ++nt) {
      const int bcol = nt * 16 + col;
#pragma unroll
      for (int ks = 0; ks < 2; ++ks)
#pragma unroll
        for (int e = 0; e < 8; ++e) {
          const float v = z_lds[bcol][ks * 32 + q4 * 8 + e];
          const uint_t h = __float_as_uint(v) >> 16;
          Bh[nt][ks][e] = (short)h;
          Bl[nt][ks][e] = (short)(__float_as_uint(v - __uint_as_float(h << 16)) >> 16);
        }
#pragma unroll
      for (int ci = 0; ci < 16; ++ci)
        zc[nt][ci] = z_lds[bcol][(ci >> 2) * 16 + 4 * q4 + (ci & 3)];
    }

    const bf16x8* __restrict__ gp =
        (const bf16x8*)gpk + (size_t)wv * 16 * 16 * 64 + lane;
#pragma unroll 1
    for (int kloc = 0; kloc < 16; ++kloc) {
      const int k = wv * 16 + kloc;
      const bf16x8* __restrict__ gk2 = gp + (size_t)kloc * 1024;
      // hoist all 16 fragment loads (coalesced 1KB each) for latency overlap
      bf16x8 A[4][4];
#pragma unroll
      for (int mtp = 0; mtp < 4; ++mtp)
#pragma unroll
        for (int s = 0; s < 4; ++s) A[mtp][s] = gk2[(mtp * 4 + s) * 64];

      float ap[4] = {0.f, 0.f, 0.f, 0.f};
#pragma unroll
      for (int mtp = 0; mtp < 4; ++mtp) {
#pragma unroll
        for (int nt = 0; nt < 4; ++nt) {
          f32x4 C = {0.f, 0.f, 0.f, 0.f};
          C = __builtin_amdgcn_mfma_f32_16x16x32_bf16(A[mtp][0], Bh[nt][0], C, 0, 0, 0);
          C = __builtin_amdgcn_mfma_f32_16x16x32_bf16(A[mtp][0], Bl[nt][0], C, 0, 0, 0);
          C = __builtin_amdgcn_mfma_f32_16x16x32_bf16(A[mtp][1], Bh[nt][0], C, 0, 0, 0);
          C = __builtin_amdgcn_mfma_f32_16x16x32_bf16(A[mtp][2], Bh[nt][1], C, 0, 0, 0);
          C = __builtin_amdgcn_mfma_f32_16x16x32_bf16(A[mtp][2], Bl[nt][1], C, 0, 0, 0);
          C = __builtin_amdgcn_mfma_f32_16x16x32_bf16(A[mtp][3], Bh[nt][1], C, 0, 0, 0);
          ap[nt] += C[0] * zc[nt][mtp * 4 + 0] + C[1] * zc[nt][mtp * 4 + 1] +
                    C[2] * zc[nt][mtp * 4 + 2] + C[3] * zc[nt][mtp * 4 + 3];
        }
      }
#pragma unroll
      for (int nt = 0; nt < 4; ++nt) {
        float a = ap[nt];
        a += __shfl_xor(a, 16, 64);
        a += __shfl_xor(a, 32, 64);
        if (q4 == 0) q_lds[nt * 16 + col][k] = a;
      }
    }
  }

  // ---- feature term: facc[jn] = sum_f feat[b][f]*M[n][f], n = wv + 8*jn ----
  float facc[8] = {0.f, 0.f, 0.f, 0.f, 0.f, 0.f, 0.f, 0.f};
  for (int c = 0; c < 8; ++c) {
    __syncthreads();  // WAR on fchunk; first iter also orders q_lds writes
    for (int i = t; i < 64 * 32; i += 512) {
      const int r = i >> 5, cc = i & 31;
      fchunk[r][cc] = feat[(size_t)(b0 + r) * F_DIM + c * 32 + cc];
    }
    __syncthreads();
#pragma unroll
    for (int fb = 0; fb < 32; fb += 8) {
      float rf[8];
#pragma unroll
      for (int u = 0; u < 8; ++u) rf[u] = fchunk[lane][fb + u];
#pragma unroll
      for (int jn = 0; jn < 8; ++jn) {
        const float* __restrict__ Mn = Mf + (wv + 8 * jn) * F_DIM + c * 32 + fb;
#pragma unroll
        for (int u = 0; u < 8; ++u) facc[jn] = fmaf(rf[u], Mn[u], facc[jn]);
      }
    }
  }
  __syncthreads();  // q_lds complete + fchunk done before reads below

  // ---- per-row scalars ----
  float zr[64];
#pragma unroll
  for (int j = 0; j < 64; ++j) zr[j] = z_lds[lane][j];
  double z_sq;
  {
    double a0 = 0.0, a1 = 0.0;
#pragma unroll
    for (int i = 0; i < 64; i += 2) {
      a0 = fma((double)zr[i], (double)zr[i], a0);
      a1 = fma((double)zr[i + 1], (double)zr[i + 1], a1);
    }
    z_sq = a0 + a1;
  }
  const double EPS = 0.001;
  const double SQRTK = sqrt(128.0);
  double tau = SQRTK * fmax(1.0 - z_sq, 0.001) * 0.5;
  tau = fmax(tau, 0.01);
  const double r2 = fmin(z_sq, 1.0 - EPS);
  const double lam = 2.0 / (1.0 - r2 + EPS);

  // ---- q . cq dot, n = wv + 8*jn ----
  float qd[8] = {0.f, 0.f, 0.f, 0.f, 0.f, 0.f, 0.f, 0.f};
#pragma unroll 4
  for (int kq = 0; kq < 128; kq += 4) {
    const float q0 = q_lds[lane][kq + 0], q1 = q_lds[lane][kq + 1];
    const float q2 = q_lds[lane][kq + 2], q3 = q_lds[lane][kq + 3];
#pragma unroll
    for (int jn = 0; jn < 8; ++jn) {
      const float* __restrict__ cqn = cq + (wv + 8 * jn) * K_DIM;
      qd[jn] = fmaf(q0, cqn[kq + 0], qd[jn]);
      qd[jn] = fmaf(q1, cqn[kq + 1], qd[jn]);
      qd[jn] = fmaf(q2, cqn[kq + 2], qd[jn]);
      qd[jn] = fmaf(q3, cqn[kq + 3], qd[jn]);
    }
  }

  // ---- phase 2: scores ----
  double sc[8];
#pragma unroll 1
  for (int jn = 0; jn < 8; ++jn) {
    const int n = wv + 8 * jn;
    const float* __restrict__ cqn = cq + n * K_DIM;
    double zc0 = 0.0, zc1 = 0.0;
    float l0 = 0.f, l1 = 0.f;
    const float* __restrict__ w2n = W2 + n * D_DIM;
#pragma unroll
    for (int i = 0; i < 64; i += 2) {
      zc0 = fma((double)zr[i], (double)cqn[i], zc0);
      zc1 = fma((double)zr[i + 1], (double)cqn[i + 1], zc1);
      l0 = fmaf(zr[i], w2n[i], l0);
      l1 = fmaf(zr[i + 1], w2n[i + 1], l1);
    }
    const double c_sq = csqd[n];
    double dist_sq = z_sq + c_sq - 2.0 * (zc0 + zc1);
    const double denom = (1.0 - z_sq) * (1.0 - c_sq);
    double arg = 1.0 + 2.0 * dist_sq / (denom + EPS);
    arg = fmax(arg, 1.0 + EPS);
    const double dist = log(arg + sqrt(arg * arg - 1.0));
    const double qtot = (double)qd[jn] + (double)facc[jn] + (double)(l0 + l1) + biasd[n];
    sc[jn] = -dist / tau + (qtot / lam) / SQRTK;
  }
  __syncthreads();  // all q_lds reads done before s_lds overlay
#pragma unroll
  for (int jn = 0; jn < 8; ++jn) s_lds[lane][wv + 8 * jn] = sc[jn];
  __syncthreads();

  // ---- phase 3: softmax + argmax ----
  if (t < 64) {
    const int b = t;
    double mx = s_lds[b][0];
    int am = 0;
#pragma unroll 4
    for (int n = 1; n < 64; ++n) {
      const double v = s_lds[b][n];
      if (v > mx) { mx = v; am = n; }
    }
    double sum = 0.0;
#pragma unroll 4
    for (int n = 0; n < 64; ++n) {
      const double e = exp(s_lds[b][n] - mx);
      s_lds[b][n] = e;
      sum += e;
    }
    sum_lds[b] = sum;
    arg_lds[b] = am;
  }
  __syncthreads();
  for (int idx = t; idx < 64 * 64; idx += 512) {
    const int b = idx >> 6, n = idx & 63;
    out[(size_t)(b0 + b) * NC_DIM + n] = (float)(s_lds[b][n] / sum_lds[b]);
  }
  if (t < 64) out[(size_t)B_TOT * NC_DIM + b0 + t] = (float)arg_lds[t];
}

extern "C" void kernel_launch(void* const* d_in, const int* in_sizes, int n_in,
                              void* d_out, int out_size, void* d_ws, size_t ws_size,
                              hipStream_t stream) {
  const float* z = (const float*)d_in[0];
  const float* feat = (const float*)d_in[1];
  const float* qzw = (const float*)d_in[2];
  const float* qzb = (const float*)d_in[3];
  const float* qfw = (const float*)d_in[4];
  const float* qfb = (const float*)d_in[5];
  const float* gamma = (const float*)d_in[6];
  const float* cq = (const float*)d_in[7];
  float* out = (float*)d_out;
  char* ws = (char*)d_ws;

  prep_kernel<<<dim3(256), dim3(256), 0, stream>>>(gamma, qfw, cq, qzw, qzb, qfb, ws);
  fused_kernel<<<dim3(B_TOT / 64), dim3(512), 0, stream>>>(z, feat, cq, ws, out);
}

// Round 4
// 190.710 us; speedup vs baseline: 3.5192x; 1.0511x over previous
//
#include <hip/hip_runtime.h>
#include <hip/hip_bf16.h>
#include <cmath>
#include <cstring>

#define B_TOT 16384
#define NSTEPS 181

typedef unsigned int uint_t;
typedef unsigned short ushort_t;
typedef __attribute__((ext_vector_type(8))) short bf16x8;
typedef __attribute__((ext_vector_type(16))) float f32x16;

// workspace layout (bytes); total 1792000
#define WS_TAB 0          // uint32[192]
#define WS_CSQ 1024       // double[64]
#define WS_S   2048       // float[64][4096] = 1 MiB
#define WS_PPK 1050624    // A-packs: 181 steps * 4 KiB = 741376
// pack frag addr: ((s*4 + mt*2 + plane)*64 + lane)*16 ; plane 0=hi 1=lo
// lane (r=lane&31,h=lane>>5) holds P[n=mt*32+r][kappa = s*16 + h*8 + e]

// ---------- prep 1: S[n][cell] = sum_k cq[n,k]*gamma[k][cell], fp32 ----------
__global__ __launch_bounds__(256) void prep_s(const float* __restrict__ g,
                                              const float* __restrict__ cq,
                                              char* __restrict__ ws) {
  float* S = (float*)(ws + WS_S);
  const int ns = blockIdx.x >> 6, J = blockIdx.x & 63, t = threadIdx.x;
  const int n = ns * 16 + (t >> 4);
  const int c0 = J * 64 + (t & 15) * 4;
  const float* __restrict__ cqn = cq + n * 128;
  float4 acc = {0.f, 0.f, 0.f, 0.f};
#pragma unroll 4
  for (int k = 0; k < 128; ++k) {
    const float4 gv = *(const float4*)(g + (size_t)k * 4096 + c0);
    const float w = cqn[k];
    acc.x = fmaf(w, gv.x, acc.x);
    acc.y = fmaf(w, gv.y, acc.y);
    acc.z = fmaf(w, gv.z, acc.z);
    acc.w = fmaf(w, gv.w, acc.w);
  }
  *(float4*)(S + (size_t)n * 4096 + c0) = acc;
}

// ---------- prep 2: build bf16 hi/lo A-packs + tab + csq ----------
__global__ __launch_bounds__(256) void prep_pack(
    const float* __restrict__ qfw, const float* __restrict__ cq,
    const float* __restrict__ qzw, const float* __restrict__ qzb,
    const float* __restrict__ qfb, char* __restrict__ ws) {
  __shared__ float Sl[4096];
  __shared__ uint_t tabl[192];
  const int n = blockIdx.x, t = threadIdx.x;
  const float* __restrict__ S = (const float*)(ws + WS_S) + (size_t)n * 4096;
  for (int i = t; i < 4096; i += 256) Sl[i] = S[i];
  if (t < 64) {
    const int i = t;
    const int start = (i < 16) ? 4 * i
                     : (i < 32) ? 64 + 3 * (i - 16)
                     : (i < 48) ? 112 + 2 * (i - 32)
                                : 144 + (i - 48);
    const int nst = 4 - (i >> 4);
    for (int u = 0; u < nst; ++u)
      tabl[start + u] = (0u << 16) | ((uint_t)i << 8) | (uint_t)(16 * ((i >> 4) + u));
  } else if (t < 80) tabl[160 + (t - 64)] = (1u << 16) | (uint_t)((t - 64) * 16);
  else if (t < 84)   tabl[176 + (t - 80)] = (2u << 16) | (uint_t)((t - 80) * 16);
  else if (t == 84)  tabl[180] = (3u << 16);
  else if (t < 96)   tabl[181 + (t - 85)] = 0;
  __syncthreads();
  if (n == 0 && t < 192) ((uint_t*)(ws + WS_TAB))[t] = tabl[t];

  const int mt = n >> 5, r = n & 31;
  auto wpack = [&](int s, int jo, float val) {
    const __hip_bfloat16 hb = __float2bfloat16(val);
    const float hf = __bfloat162float(hb);
    const __hip_bfloat16 lb = __float2bfloat16(val - hf);
    ushort_t hu, lu;
    memcpy(&hu, &hb, 2);
    memcpy(&lu, &lb, 2);
    const size_t base =
        (((size_t)s * 4 + mt * 2) * 64 + ((jo >> 3) & 1) * 32 + r) * 16 + (jo & 7) * 2;
    *(ushort_t*)(ws + WS_PPK + base) = hu;
    *(ushort_t*)(ws + WS_PPK + base + 1024) = lu;
  };

  // Z2 region: 2560 values
  for (int v = t; v < 2560; v += 256) {
    const int s = v >> 4, jo = v & 15;
    const uint_t inf = tabl[s];
    const int i = (inf >> 8) & 255, j0 = inf & 255;
    const int j = j0 + jo;
    const float val =
        (j < i) ? 0.f : ((j > i) ? Sl[i * 64 + j] + Sl[j * 64 + i] : Sl[i * 64 + i]);
    wpack(s, jo, val);
  }
  const float* __restrict__ cqn = cq + n * 128;
  // feat region: M[n][f]
  {
    const int f = t;
    float a = 0.f;
#pragma unroll 8
    for (int k = 0; k < 128; ++k) a = fmaf(qfw[k * 256 + f], cqn[k], a);
    wpack(160 + (f >> 4), f & 15, a);
  }
  // z region: W2[n][i]
  if (t < 64) {
    float a = 0.f;
#pragma unroll 8
    for (int k = 0; k < 128; ++k) a = fmaf(cqn[k], qzw[k * 64 + t], a);
    wpack(176 + (t >> 4), t & 15, a);
  }
  // const region
  if (t == 128) {
    float a = 0.f;
    for (int k = 0; k < 128; ++k) a = fmaf(qzb[k] + qfb[k], cqn[k], a);
    wpack(180, 0, a);
  } else if (t > 128 && t < 144) wpack(180, t - 128, 0.f);
  // csq
  if (t == 144) {
    double a = 0.0;
    for (int d = 0; d < 64; ++d) a = fma((double)cqn[d], (double)cqn[d], a);
    ((double*)(ws + WS_CSQ))[n] = a;
  }
}

// ---------- fused main kernel (512 threads = 8 waves, 64 rows/block) ----------
__global__ __launch_bounds__(512, 2) void fused_kernel(
    const float* __restrict__ z, const float* __restrict__ feat,
    const float* __restrict__ cq, const char* __restrict__ ws,
    float* __restrict__ out) {
  __shared__ __align__(16) unsigned char smem[35072];
  float (*z_lds)[68] = (float (*)[68])(smem);           // 17408
  float (*s_lin)[65] = (float (*)[65])(smem + 17408);   // 16640 -> 34048
  double (*s_lds)[65] = (double (*)[65])(smem);         // overlay [0,33280)
  double* sum_lds = (double*)(smem + 34048);            // reuse s_lin tail region
  int* arg_lds = (int*)(smem + 34560);

  const int t = threadIdx.x, lane = t & 63;
  const int wv = __builtin_amdgcn_readfirstlane(t >> 6);  // 0..7
  const int b0 = blockIdx.x * 64;
  const int h = lane >> 5, c = lane & 31;

  // stage z (cols 64..67 zeroed) + zero s_lin
  for (int i = t; i < 4096; i += 512) z_lds[i >> 6][i & 63] = z[(size_t)b0 * 64 + i];
  if (t < 256) z_lds[t >> 2][64 + (t & 3)] = 0.f;
  for (int i = t; i < 64 * 65; i += 512) ((float*)s_lin)[i] = 0.f;
  __syncthreads();

  // ---- single GEMM: s_lin[b][n] = q[b]·cq_n  (K-split by 8 waves) ----
  const bf16x8* __restrict__ pp = (const bf16x8*)(ws + WS_PPK);
  const uint_t* __restrict__ tab = (const uint_t*)(ws + WS_TAB);
  f32x16 acc[2][2] = {};
#pragma unroll 1
  for (int it = 0; it < 23; ++it) {
    const int s = wv + it * 8;
    if (s >= NSTEPS) break;
    const uint_t inf = tab[s];
    const int mode = inf >> 16, i_idx = (inf >> 8) & 255, p0 = inf & 255;
    const bf16x8 Ah0 = pp[((size_t)s * 4 + 0) * 64 + lane];
    const bf16x8 Al0 = pp[((size_t)s * 4 + 1) * 64 + lane];
    const bf16x8 Ah1 = pp[((size_t)s * 4 + 2) * 64 + lane];
    const bf16x8 Al1 = pp[((size_t)s * 4 + 3) * 64 + lane];
#pragma unroll
    for (int nt = 0; nt < 2; ++nt) {
      const int bl = nt * 32 + c;
      float xv[8];
      if (mode == 0) {
        const float zi = z_lds[bl][i_idx];
        const float* __restrict__ zp = &z_lds[bl][p0 + h * 8];
        const float4 a = *(const float4*)zp, b2 = *(const float4*)(zp + 4);
        xv[0] = zi * a.x; xv[1] = zi * a.y; xv[2] = zi * a.z; xv[3] = zi * a.w;
        xv[4] = zi * b2.x; xv[5] = zi * b2.y; xv[6] = zi * b2.z; xv[7] = zi * b2.w;
      } else if (mode == 1) {
        const float* __restrict__ fp = feat + (size_t)(b0 + bl) * 256 + p0 + h * 8;
        const float4 a = *(const float4*)fp, b2 = *(const float4*)(fp + 4);
        xv[0] = a.x; xv[1] = a.y; xv[2] = a.z; xv[3] = a.w;
        xv[4] = b2.x; xv[5] = b2.y; xv[6] = b2.z; xv[7] = b2.w;
      } else if (mode == 2) {
        const float* __restrict__ zp = &z_lds[bl][p0 + h * 8];
        const float4 a = *(const float4*)zp, b2 = *(const float4*)(zp + 4);
        xv[0] = a.x; xv[1] = a.y; xv[2] = a.z; xv[3] = a.w;
        xv[4] = b2.x; xv[5] = b2.y; xv[6] = b2.z; xv[7] = b2.w;
      } else {
        xv[0] = (h == 0) ? 1.f : 0.f;
        xv[1] = xv[2] = xv[3] = xv[4] = xv[5] = xv[6] = xv[7] = 0.f;
      }
      // RNE hi/lo split
      uint_t bhw[4], blw[4];
#pragma unroll
      for (int e2 = 0; e2 < 4; ++e2) {
        const float2 xp = {xv[2 * e2], xv[2 * e2 + 1]};
        const __hip_bfloat162 hb2 = __float22bfloat162_rn(xp);
        uint_t hw;
        memcpy(&hw, &hb2, 4);
        const float h0 = __uint_as_float(hw << 16);
        const float h1 = __uint_as_float(hw & 0xffff0000u);
        const float2 lp = {xp.x - h0, xp.y - h1};
        const __hip_bfloat162 lb2 = __float22bfloat162_rn(lp);
        uint_t lw;
        memcpy(&lw, &lb2, 4);
        bhw[e2] = hw;
        blw[e2] = lw;
      }
      bf16x8 Bh, Bl;
      memcpy(&Bh, bhw, 16);
      memcpy(&Bl, blw, 16);
      acc[0][nt] = __builtin_amdgcn_mfma_f32_32x32x16_bf16(Ah0, Bh, acc[0][nt], 0, 0, 0);
      acc[0][nt] = __builtin_amdgcn_mfma_f32_32x32x16_bf16(Ah0, Bl, acc[0][nt], 0, 0, 0);
      acc[0][nt] = __builtin_amdgcn_mfma_f32_32x32x16_bf16(Al0, Bh, acc[0][nt], 0, 0, 0);
      acc[1][nt] = __builtin_amdgcn_mfma_f32_32x32x16_bf16(Ah1, Bh, acc[1][nt], 0, 0, 0);
      acc[1][nt] = __builtin_amdgcn_mfma_f32_32x32x16_bf16(Ah1, Bl, acc[1][nt], 0, 0, 0);
      acc[1][nt] = __builtin_amdgcn_mfma_f32_32x32x16_bf16(Al1, Bh, acc[1][nt], 0, 0, 0);
    }
  }
  // fold K-split partials: C layout col=lane&31, row=(r&3)+8*(r>>2)+4*h
#pragma unroll
  for (int mt = 0; mt < 2; ++mt)
#pragma unroll
    for (int nt = 0; nt < 2; ++nt)
#pragma unroll
      for (int r = 0; r < 16; ++r) {
        const int n = mt * 32 + (r & 3) + 8 * (r >> 2) + 4 * h;
        atomicAdd(&s_lin[nt * 32 + c][n], acc[mt][nt][r]);
      }
  __syncthreads();

  // ---- tail: fp64 hyperbolic part + combine ----
  float zr[64];
#pragma unroll
  for (int j = 0; j < 64; ++j) zr[j] = z_lds[lane][j];
  float lin[8];
#pragma unroll
  for (int jn = 0; jn < 8; ++jn) lin[jn] = s_lin[lane][wv + 8 * jn];

  double z_sq;
  {
    double a0 = 0.0, a1 = 0.0;
#pragma unroll
    for (int i = 0; i < 64; i += 2) {
      a0 = fma((double)zr[i], (double)zr[i], a0);
      a1 = fma((double)zr[i + 1], (double)zr[i + 1], a1);
    }
    z_sq = a0 + a1;
  }
  const double EPS = 0.001;
  const double SQRTK = sqrt(128.0);
  double tau = SQRTK * fmax(1.0 - z_sq, 0.001) * 0.5;
  tau = fmax(tau, 0.01);
  const double r2 = fmin(z_sq, 1.0 - EPS);
  const double lam = 2.0 / (1.0 - r2 + EPS);
  const double* __restrict__ csqd = (const double*)(ws + WS_CSQ);

  double sc[8];
#pragma unroll 1
  for (int jn = 0; jn < 8; ++jn) {
    const int n = wv + 8 * jn;
    const float* __restrict__ cqn = cq + n * 128;  // wave-uniform -> s_load
    double zc0 = 0.0, zc1 = 0.0;
#pragma unroll
    for (int i = 0; i < 64; i += 2) {
      zc0 = fma((double)zr[i], (double)cqn[i], zc0);
      zc1 = fma((double)zr[i + 1], (double)cqn[i + 1], zc1);
    }
    const double c_sq = csqd[n];
    const double dist_sq = z_sq + c_sq - 2.0 * (zc0 + zc1);
    const double denom = (1.0 - z_sq) * (1.0 - c_sq);
    double arg = 1.0 + 2.0 * dist_sq / (denom + EPS);
    arg = fmax(arg, 1.0 + EPS);
    const double dist = log(arg + sqrt(arg * arg - 1.0));
    sc[jn] = -dist / tau + ((double)lin[jn] / lam) / SQRTK;
  }
  __syncthreads();  // all z_lds/s_lin reads done before s_lds overlay
#pragma unroll
  for (int jn = 0; jn < 8; ++jn) s_lds[lane][wv + 8 * jn] = sc[jn];
  __syncthreads();

  // ---- softmax + argmax ----
  if (t < 64) {
    const int b = t;
    double mx = s_lds[b][0];
    int am = 0;
#pragma unroll 4
    for (int n = 1; n < 64; ++n) {
      const double v = s_lds[b][n];
      if (v > mx) { mx = v; am = n; }
    }
    double sum = 0.0;
#pragma unroll 4
    for (int n = 0; n < 64; ++n) {
      const double e = exp(s_lds[b][n] - mx);
      s_lds[b][n] = e;
      sum += e;
    }
    sum_lds[b] = sum;
    arg_lds[b] = am;
  }
  __syncthreads();
  for (int idx = t; idx < 4096; idx += 512) {
    const int b = idx >> 6, n = idx & 63;
    out[(size_t)(b0 + b) * 64 + n] = (float)(s_lds[b][n] / sum_lds[b]);
  }
  if (t < 64) out[(size_t)B_TOT * 64 + b0 + t] = (float)arg_lds[t];
}

extern "C" void kernel_launch(void* const* d_in, const int* in_sizes, int n_in,
                              void* d_out, int out_size, void* d_ws, size_t ws_size,
                              hipStream_t stream) {
  const float* z = (const float*)d_in[0];
  const float* feat = (const float*)d_in[1];
  const float* qzw = (const float*)d_in[2];
  const float* qzb = (const float*)d_in[3];
  const float* qfw = (const float*)d_in[4];
  const float* qfb = (const float*)d_in[5];
  const float* gamma = (const float*)d_in[6];
  const float* cq = (const float*)d_in[7];
  float* out = (float*)d_out;
  char* ws = (char*)d_ws;

  prep_s<<<dim3(256), dim3(256), 0, stream>>>(gamma, cq, ws);
  prep_pack<<<dim3(64), dim3(256), 0, stream>>>(qfw, cq, qzw, qzb, qfb, ws);
  fused_kernel<<<dim3(B_TOT / 64), dim3(512), 0, stream>>>(z, feat, cq, ws, out);
}